// Round 6
// baseline (736.649 us; speedup 1.0000x reference)
//
#include <hip/hip_runtime.h>
#include <cmath>

typedef unsigned long long u64;
typedef unsigned int u32;
typedef unsigned char u8;

#define SCAN_BLOCK 256
#define SCAN_ELEMS 8
#define SCAN_TILE (SCAN_BLOCK * SCAN_ELEMS)

__constant__ int d_NUMTRI[16] = {0,1,1,2,1,2,2,1,1,2,2,1,2,1,1,0};
__constant__ int d_TRI[16][6] = {
 {-1,-1,-1,-1,-1,-1},{1,0,2,-1,-1,-1},{4,0,3,-1,-1,-1},{1,4,2,1,3,4},
 {3,1,5,-1,-1,-1},{2,3,0,2,5,3},{1,4,0,1,5,4},{4,2,5,-1,-1,-1},
 {4,5,2,-1,-1,-1},{4,1,0,4,5,1},{3,2,0,3,5,2},{1,3,5,-1,-1,-1},
 {4,1,2,4,3,1},{3,0,4,-1,-1,-1},{2,0,1,-1,-1,-1},{-1,-1,-1,-1,-1,-1}};
__constant__ int d_E0[6] = {0,0,0,1,1,2};
__constant__ int d_E1[6] = {1,2,3,2,3,3};

// ---------------- exclusive scan, templated element type ----------------
// NOTE: tet m1/m2 scan MUST be u64 — running m1 total needs 19 bits packed at
// bit 21 (overflowed u32 in round 3).
template <typename T>
__global__ void scanA_t(const T* in, T* out, int n, T* blockSums) {
    __shared__ T tsum[SCAN_BLOCK];
    int tbase = blockIdx.x * SCAN_TILE + threadIdx.x * SCAN_ELEMS;
    T vals[SCAN_ELEMS];
    T run = 0;
    for (int k = 0; k < SCAN_ELEMS; ++k) {
        int i = tbase + k;
        T v = (i < n) ? in[i] : (T)0;
        vals[k] = run;
        run += v;
    }
    tsum[threadIdx.x] = run;
    __syncthreads();
    for (int off = 1; off < SCAN_BLOCK; off <<= 1) {
        T v = (threadIdx.x >= (unsigned)off) ? tsum[threadIdx.x - off] : (T)0;
        __syncthreads();
        tsum[threadIdx.x] += v;
        __syncthreads();
    }
    T texcl = (threadIdx.x == 0) ? (T)0 : tsum[threadIdx.x - 1];
    for (int k = 0; k < SCAN_ELEMS; ++k) {
        int i = tbase + k;
        if (i < n) out[i] = texcl + vals[k];
    }
    if (threadIdx.x == SCAN_BLOCK - 1) blockSums[blockIdx.x] = tsum[SCAN_BLOCK - 1];
}

// scanA over PAD4(bucketCnt) — pads each count to a multiple of 4 on the fly
// (replaces the separate padCnt array + its writer).
__global__ void scanA_pad(const u32* in, u32* out, int n, u32* blockSums) {
    __shared__ u32 tsum[SCAN_BLOCK];
    int tbase = blockIdx.x * SCAN_TILE + threadIdx.x * SCAN_ELEMS;
    u32 vals[SCAN_ELEMS];
    u32 run = 0;
    for (int k = 0; k < SCAN_ELEMS; ++k) {
        int i = tbase + k;
        u32 v = (i < n) ? ((in[i] + 3u) & ~3u) : 0u;
        vals[k] = run;
        run += v;
    }
    tsum[threadIdx.x] = run;
    __syncthreads();
    for (int off = 1; off < SCAN_BLOCK; off <<= 1) {
        u32 v = (threadIdx.x >= (unsigned)off) ? tsum[threadIdx.x - off] : 0u;
        __syncthreads();
        tsum[threadIdx.x] += v;
        __syncthreads();
    }
    u32 texcl = (threadIdx.x == 0) ? 0u : tsum[threadIdx.x - 1];
    for (int k = 0; k < SCAN_ELEMS; ++k) {
        int i = tbase + k;
        if (i < n) out[i] = texcl + vals[k];
    }
    if (threadIdx.x == SCAN_BLOCK - 1) blockSums[blockIdx.x] = tsum[SCAN_BLOCK - 1];
}

template <typename T>
__global__ void scanB_t(T* bs, int nb, T* totalOut) {
    __shared__ T sh[2048];
    for (int i = threadIdx.x; i < 2048; i += 256) sh[i] = (i < nb) ? bs[i] : (T)0;
    __syncthreads();
    for (int off = 1; off < 2048; off <<= 1) {
        T v[8];
        for (int k = 0; k < 8; ++k) {
            int i = threadIdx.x + k * 256;
            v[k] = (i >= off) ? sh[i - off] : (T)0;
        }
        __syncthreads();
        for (int k = 0; k < 8; ++k) sh[threadIdx.x + k * 256] += v[k];
        __syncthreads();
    }
    for (int i = threadIdx.x; i < nb; i += 256) bs[i] = (i == 0) ? (T)0 : sh[i - 1];
    if (threadIdx.x == 0 && totalOut) *totalOut = (nb > 0) ? sh[nb - 1] : (T)0;
}

template <typename T>
__global__ void scanC_t(T* out, int n, const T* bs) {
    int base = blockIdx.x * SCAN_TILE;
    T add = bs[blockIdx.x];
    int end = base + SCAN_TILE; if (end > n) end = n;
    for (int i = base + threadIdx.x; i < end; i += SCAN_BLOCK) out[i] += add;
}

// scanC that also emits a second copy (atomic cursor array for k_fill).
__global__ void scanC2(u32* out, u32* cur, int n, const u32* bs) {
    int base = blockIdx.x * SCAN_TILE;
    u32 add = bs[blockIdx.x];
    int end = base + SCAN_TILE; if (end > n) end = n;
    for (int i = base + threadIdx.x; i < end; i += SCAN_BLOCK) {
        u32 x = out[i] + add;
        out[i] = x;
        cur[i] = x;
    }
}

// ---------------- pipeline ----------------
// Pass 1: classify tets; count crossing edges per min-endpoint bucket via
// GLOBAL atomics (bucketCnt is 800KB, L2-resident; ~3M adds over 200k
// addresses). Replaces the whole 2-level bin histogram/scan/scatter chain
// (blockHist + nHist scan + k_bincount + k_binscatter: ~5 dispatches,
// ~140MB traffic). Also zeroes the big-bucket counter (graph-replay safe;
// bucketCnt itself is zeroed by a hipMemsetAsync before this kernel).
__global__ __launch_bounds__(256) void k_classify(
    const int* tet, const float* sdf, u8* ti8, u64* tetPack,
    u32* bucketCnt, u32* bigCnt, int T)
{
    int t = blockIdx.x * 256 + threadIdx.x;
    if (t == 0) *bigCnt = 0;
    if (t >= T) return;
    int4 q = reinterpret_cast<const int4*>(tet)[t];
    int ti = (sdf[q.x] > 0.0f ? 1 : 0) | (sdf[q.y] > 0.0f ? 2 : 0) |
             (sdf[q.z] > 0.0f ? 4 : 0) | (sdf[q.w] > 0.0f ? 8 : 0);
    ti8[t] = (u8)ti;
    int nt = d_NUMTRI[ti];
    tetPack[t] = ((u64)(nt == 1 ? 1 : 0) << 21) | (u64)(nt == 2 ? 1 : 0);
    if (nt != 0) {
        int idx[4] = {q.x, q.y, q.z, q.w};
        #pragma unroll
        for (int e = 0; e < 6; ++e) {
            int e0 = d_E0[e], e1 = d_E1[e];
            if (((ti >> e0) ^ (ti >> e1)) & 1) {
                int a = idx[e0], b = idx[e1];
                int mn = a < b ? a : b;
                atomicAdd(&bucketCnt[mn], 1u);
            }
        }
    }
}

// Pass 2: scatter (mx, prov=6t+e) records directly into each bucket's
// contiguous window via global cursor atomics. Intra-bucket order is
// irrelevant — k_sortdedup rank-sorts the bucket anyway.
__global__ __launch_bounds__(256) void k_fill(
    const int* tet, const u8* ti8, u32* cursor, uint2* rec2, int T)
{
    int t = blockIdx.x * 256 + threadIdx.x;
    if (t >= T) return;
    int ti = ti8[t];
    if (d_NUMTRI[ti] == 0) return;
    int4 q = reinterpret_cast<const int4*>(tet)[t];
    int idx[4] = {q.x, q.y, q.z, q.w};
    #pragma unroll
    for (int e = 0; e < 6; ++e) {
        int e0 = d_E0[e], e1 = d_E1[e];
        if (((ti >> e0) ^ (ti >> e1)) & 1) {
            int a = idx[e0], b = idx[e1];
            int mn = a < b ? a : b;
            int mx = a < b ? b : a;
            u32 slot = atomicAdd(&cursor[mn], 1u);
            rec2[slot] = make_uint2((u32)mx, 6u * (u32)t + (u32)e);
        }
    }
}

// HOT sort+dedup — R2's measured-best structure (93us): ONE bucket per
// 64-lane wave (n is wave-UNIFORM -> SGPR loop, no exec-mask churn; the R5
// 32-lane-segment variant made n divergent and regressed to 134us), 4
// buckets per 256-block, zero LDS, no barriers, n<=64 inline, n>64 to
// bigList. Plain idxmap stores (L2 write-allocate absorbs the 4B scatter;
// k_faces re-reads idxmap — NT stores were R3's 231us disaster).
__global__ __launch_bounds__(256) void k_sortdedup(
    const u32* bucketCnt, const u32* bucketStart, uint2* rec2,
    u32* idxmap, u32* crossCnt, u32* bigList, u32* bigCnt, int V)
{
    int v = blockIdx.x * 4 + (threadIdx.x >> 6);
    if (v >= V) return;
    int lane = threadIdx.x & 63;
    int n = (int)bucketCnt[v];
    if (n == 0) { if (lane == 0) crossCnt[v] = 0; return; }
    if (n > 64) {
        if (lane == 0) bigList[atomicAdd(bigCnt, 1u)] = (u32)v;
        return;
    }
    long long start = (long long)bucketStart[v];
    uint2 rp = (lane < n) ? rec2[start + lane] : make_uint2(0xFFFFFFFFu, 0u);
    u32 key = rp.x, prov = rp.y;
    int rank = 0;
    for (int j = 0; j < n; ++j) {               // wave-uniform bound, avg ~15
        u32 kj = (u32)__shfl((int)key, j);
        rank += (kj < key || (kj == key && j < lane)) ? 1 : 0;
    }
    u32 sorted = (u32)__builtin_amdgcn_ds_permute(rank << 2, (int)key);
    u32 prev = (u32)__shfl((int)sorted, lane - 1);
    bool nf = (lane < n) && (lane == 0 || prev != sorted);
    u64 m = __ballot(nf);
    int idx = __popcll(m & ((1ull << lane) - 1ull));
    if (nf) rec2[start + idx].x = sorted;
    int ldSorted = nf ? idx : idx - 1;          // dedup idx at sorted pos lane
    int ldOrig = __shfl(ldSorted, rank);        // my record sits at pos rank
    if (lane < n) idxmap[prov] = (u32)ldOrig;
    if (lane == 0) crossCnt[v] = (u32)__popcll(m);
}

// Overflow path (64<n<=256, ~0-100 buckets): one FULL WAVE per bucket,
// register-chunked (4x64) two-pass shfl rank/dedup — no LDS, no serial work.
// R4 lesson: the lane-0 insertion-sort fallback on real buckets was a
// single-lane O(n^2) dependent-L2-chain = 207us tail. Serial path remains
// only for n>256 (needs a vertex in ~85+ tets; P~0).
__global__ __launch_bounds__(256) void k_sortbig(
    const u32* bigList, const u32* bigCnt, const u32* bucketCnt,
    const u32* bucketStart, uint2* rec2, u32* idxmap, u32* crossCnt)
{
    int nbig = (int)*bigCnt;
    int lane = threadIdx.x & 63;
    int wave = (blockIdx.x << 2) + (threadIdx.x >> 6);
    int stride = gridDim.x << 2;
    for (int b = wave; b < nbig; b += stride) {
        int v = (int)bigList[b];
        int n = (int)bucketCnt[v];
        long long start = (long long)bucketStart[v];
        if (n <= 256) {
            int chunks = (n + 63) >> 6;         // 1..4
            u32 key[4], prov[4], kf[4];
            int myi[4];
            #pragma unroll
            for (int c = 0; c < 4; ++c) {
                myi[c] = (c << 6) + lane;
                key[c] = 0xFFFFFFFFu; prov[c] = 0u;
                if (c < chunks && myi[c] < n) {
                    uint2 rp = rec2[start + myi[c]];
                    key[c] = rp.x; prov[c] = rp.y;
                }
            }
            // pass 1: does an earlier element carry my key?
            bool tie[4] = {false, false, false, false};
            #pragma unroll
            for (int c2 = 0; c2 < 4; ++c2) {
                if (c2 < chunks) {
                    int base2 = c2 << 6;
                    int lim = n - base2; if (lim > 64) lim = 64;
                    for (int j = 0; j < lim; ++j) {
                        u32 kj = (u32)__shfl((int)key[c2], j);
                        int jg = base2 + j;
                        #pragma unroll
                        for (int c = 0; c < 4; ++c) {
                            if (c < chunks)
                                tie[c] = tie[c] | (kj == key[c] && jg < myi[c]);
                        }
                    }
                }
            }
            u32 uq = 0;                          // total unique (all lanes)
            #pragma unroll
            for (int c = 0; c < 4; ++c) {
                bool isf = (c < chunks) && (myi[c] < n) && !tie[c];
                kf[c] = key[c] | (isf ? 0x80000000u : 0u);
                u64 bal = __ballot(isf);
                uq += (u32)__popcll(bal);
            }
            // pass 2: count distinct keys smaller than mine (isFirst in
            // bit31 of broadcast key; keys < 2^18 so bit31 is free)
            int uless[4] = {0, 0, 0, 0};
            #pragma unroll
            for (int c2 = 0; c2 < 4; ++c2) {
                if (c2 < chunks) {
                    int base2 = c2 << 6;
                    int lim = n - base2; if (lim > 64) lim = 64;
                    for (int j = 0; j < lim; ++j) {
                        u32 kfj = (u32)__shfl((int)kf[c2], j);
                        u32 kj = kfj & 0x7FFFFFFFu;
                        bool fj = (kfj & 0x80000000u) != 0u;
                        #pragma unroll
                        for (int c = 0; c < 4; ++c) {
                            if (c < chunks)
                                uless[c] += (fj && kj < key[c]) ? 1 : 0;
                        }
                    }
                }
            }
            #pragma unroll
            for (int c = 0; c < 4; ++c) {
                if (c < chunks && myi[c] < n) {
                    if (kf[c] & 0x80000000u)
                        rec2[start + uless[c]].x = key[c];
                    idxmap[prov[c]] = (u32)uless[c];
                }
            }
            if (lane == 0) crossCnt[v] = uq;
        } else if (lane == 0) {
            for (int i = 1; i < n; ++i) {
                uint2 kk = rec2[start + i];
                int j = i - 1;
                while (j >= 0 && rec2[start + j].x > kk.x) {
                    rec2[start + j + 1] = rec2[start + j]; --j;
                }
                rec2[start + j + 1] = kk;
            }
            int uc = 0; u32 prev = 0xFFFFFFFFu;
            for (int i = 0; i < n; ++i) {
                uint2 r = rec2[start + i];
                if (r.x != prev) { rec2[start + uc].x = r.x; ++uc; prev = r.x; }
                idxmap[r.y] = (u32)(uc - 1);
            }
            crossCnt[v] = (u32)uc;
        }
    }
}

// 32-lane segments, 8 buckets per 256-block; lane i -> unique crossing edge
// i -> vertex crossScan[v]+i. Strided loop handles u>32 (big buckets too).
__global__ __launch_bounds__(256) void k_verts(
    const u32* crossCnt, const u32* bucketStart, const uint2* rec2, const u32* crossScan,
    const float* pos, const float* sdf, float* out, int V)
{
    int v = blockIdx.x * 8 + (threadIdx.x >> 5);
    if (v >= V) return;
    int slane = threadIdx.x & 31;
    int u = (int)crossCnt[v];
    if (u == 0) return;
    long long start = (long long)bucketStart[v];
    int cBase = (int)crossScan[v];
    float s0 = sdf[v];
    float p0x = pos[3 * v], p0y = pos[3 * v + 1], p0z = pos[3 * v + 2];
    for (int i = slane; i < u; i += 32) {
        int b = (int)rec2[start + i].x;
        long long k = cBase + i;
        float s1 = sdf[b];
        float d = s0 - s1;
        float w0 = -s1 / d, w1 = s0 / d;
        out[3 * k + 0] = p0x * w0 + pos[3 * b + 0] * w1;
        out[3 * k + 1] = p0y * w0 + pos[3 * b + 1] * w1;
        out[3 * k + 2] = p0z * w0 + pos[3 * b + 2] * w1;
    }
}

// faces + uv_idx. Edge->vertex id is a direct read: idx_map[6t+e] holds the
// local dedup index within bucket(a); global id = crossScan[a] + local.
__global__ void k_faces(const int* tet, const u8* ti8, const u64* tetScan,
                        const u32* idxmap, const u32* crossScan,
                        const u64* meta0, const u32* NePtr,
                        float* out, int T, int Ngrid, long long uvFloats)
{
    int t = blockIdx.x * 256 + threadIdx.x;
    if (t >= T) return;
    int ti = ti8[t];
    int nt = d_NUMTRI[ti];
    if (nt == 0) return;

    u64 tot = *meta0;
    int C1 = (int)((tot >> 21) & 0x1fffffull);
    int C2 = (int)(tot & 0x1fffffull);
    int Ne = (int)*NePtr;
    long long facesBase = 3LL * Ne;
    long long F = (long long)C1 + 2LL * C2;
    long long uvIdxBase = facesBase + 3LL * F + uvFloats;

    int4 q = reinterpret_cast<const int4*>(tet)[t];
    int idx[4] = {q.x, q.y, q.z, q.w};
    const uint2* imp = reinterpret_cast<const uint2*>(idxmap + 6ll * t);
    uint2 r0 = imp[0], r1 = imp[1], r2 = imp[2];
    u32 im[6] = {r0.x, r0.y, r1.x, r1.y, r2.x, r2.y};
    const int* row = d_TRI[ti];

    int emap[6];
    unsigned done = 0;
    float fv[6];
    #pragma unroll
    for (int j = 0; j < 6; ++j) {
        if (j >= 3 * nt) break;
        int e = row[j];
        if (!((done >> e) & 1)) {
            done |= 1u << e;
            int a = idx[d_E0[e]], b = idx[d_E1[e]];
            if (b < a) a = b;                  // a = min endpoint = bucket
            emap[e] = (int)crossScan[a] + (int)im[e];
        }
        fv[j] = (float)emap[e];
    }

    u64 sc = tetScan[t];
    int r1s = (int)((sc >> 21) & 0x1fffffull);
    int r2s = (int)(sc & 0x1fffffull);
    int tet_idx = (t / Ngrid) * Ngrid + (t % Ngrid);

    if (nt == 1) {
        long long f = r1s;
        out[facesBase + 3 * f + 0] = fv[0];
        out[facesBase + 3 * f + 1] = fv[1];
        out[facesBase + 3 * f + 2] = fv[2];
        out[uvIdxBase + 3 * f + 0] = (float)(4 * tet_idx);
        out[uvIdxBase + 3 * f + 1] = (float)(4 * tet_idx + 1);
        out[uvIdxBase + 3 * f + 2] = (float)(4 * tet_idx + 2);
    } else {
        long long f0 = (long long)C1 + 2LL * r2s;
        out[facesBase + 3 * f0 + 0] = fv[0];
        out[facesBase + 3 * f0 + 1] = fv[1];
        out[facesBase + 3 * f0 + 2] = fv[2];
        out[facesBase + 3 * (f0 + 1) + 0] = fv[3];
        out[facesBase + 3 * (f0 + 1) + 1] = fv[4];
        out[facesBase + 3 * (f0 + 1) + 2] = fv[5];
        out[uvIdxBase + 3 * f0 + 0] = (float)(4 * tet_idx);
        out[uvIdxBase + 3 * f0 + 1] = (float)(4 * tet_idx + 1);
        out[uvIdxBase + 3 * f0 + 2] = (float)(4 * tet_idx + 2);
        out[uvIdxBase + 3 * (f0 + 1) + 0] = (float)(4 * tet_idx);
        out[uvIdxBase + 3 * (f0 + 1) + 1] = (float)(4 * tet_idx + 2);
        out[uvIdxBase + 3 * (f0 + 1) + 2] = (float)(4 * tet_idx + 3);
    }
}

__global__ void k_uvs(float* out, const u64* meta0, const u32* NePtr, int Ngrid) {
    int c = blockIdx.x * 256 + threadIdx.x;
    int total = Ngrid * Ngrid;
    if (c >= total) return;
    u64 tot = *meta0;
    int C1 = (int)((tot >> 21) & 0x1fffffull);
    int C2 = (int)(tot & 0x1fffffull);
    int Ne = (int)*NePtr;
    long long uvBase = 3LL * Ne + 3LL * ((long long)C1 + 2LL * C2);
    int i = c / Ngrid, j = c % Ngrid;
    double step = (Ngrid > 1) ? (1.0 - 1.0 / (double)Ngrid) / (double)(Ngrid - 1) : 0.0;
    float x = (float)((double)j * step);
    float y = (float)((double)i * step);
    float pad = (float)(0.9 / (double)Ngrid);
    long long o = uvBase + 8LL * c;
    out[o + 0] = x;       out[o + 1] = y;
    out[o + 2] = x + pad; out[o + 3] = y;
    out[o + 4] = x + pad; out[o + 5] = y + pad;
    out[o + 6] = x;       out[o + 7] = y + pad;
}

// ---------------- host ----------------
template <typename T>
static void run_scan_t(const T* in, T* out, int n, T* blockSums, T* totalOut,
                       hipStream_t stream) {
    int nb = (n + SCAN_TILE - 1) / SCAN_TILE;
    scanA_t<T><<<nb, SCAN_BLOCK, 0, stream>>>(in, out, n, blockSums);
    scanB_t<T><<<1, 256, 0, stream>>>(blockSums, nb, totalOut);
    scanC_t<T><<<nb, SCAN_BLOCK, 0, stream>>>(out, n, blockSums);
}

extern "C" void kernel_launch(void* const* d_in, const int* in_sizes, int n_in,
                              void* d_out, int out_size, void* d_ws, size_t ws_size,
                              hipStream_t stream) {
    const float* pos = (const float*)d_in[0];
    const float* sdf = (const float*)d_in[1];
    const int* tet = (const int*)d_in[2];
    int V = in_sizes[1];
    int T = in_sizes[2] / 4;
    float* out = (float*)d_out;

    char* p = (char*)d_ws;
    auto alloc = [&](size_t bytes) -> void* {
        void* r = (void*)p;
        p += (bytes + 255) & ~(size_t)255;
        return r;
    };
    u8*  ti8           = (u8*) alloc((size_t)T);
    u64* tetPack       = (u64*)alloc((size_t)T * 8);
    u64* tetScan       = (u64*)alloc((size_t)T * 8);
    u32* bucketCnt     = (u32*)alloc((size_t)V * 4);
    u32* bucketStart   = (u32*)alloc((size_t)V * 4);
    u32* cursor        = (u32*)alloc((size_t)V * 4);
    u32* crossCnt      = (u32*)alloc((size_t)V * 4);
    u32* crossScan     = (u32*)alloc((size_t)V * 4);
    u32* idxmap        = (u32*)alloc((size_t)6 * T * 4);
    uint2* rec2        = (uint2*)alloc(((size_t)6 * T + 4 * (size_t)V) * 8);
    u32* bigList       = (u32*)alloc((size_t)V * 4);
    u64* blockSums64   = (u64*)alloc(2048 * 8);
    u32* blockSums32   = (u32*)alloc(2048 * 4);
    u64* meta64        = (u64*)alloc(8 * 8);
    u32* NePtr         = (u32*)(meta64 + 4);
    u32* bigCnt        = (u32*)(meta64 + 6);

    long long M = (2LL * T + 1) / 2;
    int Ngrid = (int)std::sqrt((double)M);
    while ((long long)Ngrid * Ngrid < M) ++Ngrid;
    if (Ngrid < 1) Ngrid = 1;
    long long uvFloats = 8LL * Ngrid * Ngrid;

    int gT = (T + 255) / 256;
    int gV4 = (V + 3) / 4;
    int gV8 = (V + 7) / 8;
    int nbV = (V + SCAN_TILE - 1) / SCAN_TILE;

    hipMemsetAsync(bucketCnt, 0, (size_t)V * 4, stream);
    k_classify<<<gT, 256, 0, stream>>>(tet, sdf, ti8, tetPack, bucketCnt,
                                       bigCnt, T);
    run_scan_t<u64>(tetPack, tetScan, T, blockSums64, meta64, stream);
    // bucketStart = exclusive scan of PAD4(bucketCnt); cursor = copy
    scanA_pad<<<nbV, SCAN_BLOCK, 0, stream>>>(bucketCnt, bucketStart, V,
                                              blockSums32);
    scanB_t<u32><<<1, 256, 0, stream>>>(blockSums32, nbV, nullptr);
    scanC2<<<nbV, SCAN_BLOCK, 0, stream>>>(bucketStart, cursor, V, blockSums32);
    k_fill<<<gT, 256, 0, stream>>>(tet, ti8, cursor, rec2, T);
    k_sortdedup<<<gV4, 256, 0, stream>>>(bucketCnt, bucketStart, rec2,
                                         idxmap, crossCnt, bigList, bigCnt, V);
    k_sortbig<<<256, 256, 0, stream>>>(bigList, bigCnt, bucketCnt, bucketStart,
                                       rec2, idxmap, crossCnt);
    run_scan_t<u32>(crossCnt, crossScan, V, blockSums32, NePtr, stream);
    k_verts<<<gV8, 256, 0, stream>>>(crossCnt, bucketStart, rec2, crossScan,
                                     pos, sdf, out, V);
    k_faces<<<gT, 256, 0, stream>>>(tet, ti8, tetScan, idxmap, crossScan,
                                    meta64, NePtr, out, T, Ngrid, uvFloats);
    int gUV = (Ngrid * Ngrid + 255) / 256;
    k_uvs<<<gUV, 256, 0, stream>>>(out, meta64, NePtr, Ngrid);
}

// Round 7
// 459.651 us; speedup vs baseline: 1.6026x; 1.6026x over previous
//
#include <hip/hip_runtime.h>
#include <cmath>

typedef unsigned long long u64;
typedef unsigned int u32;
typedef unsigned char u8;

#define SCAN_BLOCK 256
#define SCAN_ELEMS 8
#define SCAN_TILE (SCAN_BLOCK * SCAN_ELEMS)

// counting-sort bins: 512 vertices per bin (V=200000 -> NB=391 <= 512).
// record packing (mn&511)<<18 | mx requires V <= 2^18.
#define BIN_SHIFT 9
#define BIN_VR 512
#define TETS_PER_BLOCK 2048

__constant__ int d_NUMTRI[16] = {0,1,1,2,1,2,2,1,1,2,2,1,2,1,1,0};
__constant__ int d_TRI[16][6] = {
 {-1,-1,-1,-1,-1,-1},{1,0,2,-1,-1,-1},{4,0,3,-1,-1,-1},{1,4,2,1,3,4},
 {3,1,5,-1,-1,-1},{2,3,0,2,5,3},{1,4,0,1,5,4},{4,2,5,-1,-1,-1},
 {4,5,2,-1,-1,-1},{4,1,0,4,5,1},{3,2,0,3,5,2},{1,3,5,-1,-1,-1},
 {4,1,2,4,3,1},{3,0,4,-1,-1,-1},{2,0,1,-1,-1,-1},{-1,-1,-1,-1,-1,-1}};
__constant__ int d_E0[6] = {0,0,0,1,1,2};
__constant__ int d_E1[6] = {1,2,3,2,3,3};

// ---------------- exclusive scan (2-dispatch: scanA + fused scanCf) --------
// NOTE: tet m1/m2 scan MUST be u64 — running m1 total needs 19 bits packed at
// bit 21 (overflowed u32 in an early round).
template <typename T>
__global__ void scanA_t(const T* in, T* out, int n, T* blockSums) {
    __shared__ T tsum[SCAN_BLOCK];
    int tbase = blockIdx.x * SCAN_TILE + threadIdx.x * SCAN_ELEMS;
    T vals[SCAN_ELEMS];
    T run = 0;
    for (int k = 0; k < SCAN_ELEMS; ++k) {
        int i = tbase + k;
        T v = (i < n) ? in[i] : (T)0;
        vals[k] = run;
        run += v;
    }
    tsum[threadIdx.x] = run;
    __syncthreads();
    for (int off = 1; off < SCAN_BLOCK; off <<= 1) {
        T v = (threadIdx.x >= (unsigned)off) ? tsum[threadIdx.x - off] : (T)0;
        __syncthreads();
        tsum[threadIdx.x] += v;
        __syncthreads();
    }
    T texcl = (threadIdx.x == 0) ? (T)0 : tsum[threadIdx.x - 1];
    for (int k = 0; k < SCAN_ELEMS; ++k) {
        int i = tbase + k;
        if (i < n) out[i] = texcl + vals[k];
    }
    if (threadIdx.x == SCAN_BLOCK - 1) blockSums[blockIdx.x] = tsum[SCAN_BLOCK - 1];
}

// Fused scanB+scanC: every block redundantly scans the <=2048 blockSums in
// LDS (<=16KB read, L2-hit) and adds its exclusive prefix. Kills the
// 1-block scanB dispatch (launch-latency-bound) per chain. Block 0 also
// emits the grand total.
template <typename T>
__global__ void scanCf_t(T* out, int n, const T* bs, int nb, T* totalOut) {
    __shared__ T sh[2048];
    for (int i = threadIdx.x; i < 2048; i += 256) sh[i] = (i < nb) ? bs[i] : (T)0;
    __syncthreads();
    for (int off = 1; off < 2048; off <<= 1) {
        T v[8];
        for (int k = 0; k < 8; ++k) {
            int i = threadIdx.x + k * 256;
            v[k] = (i >= off) ? sh[i - off] : (T)0;
        }
        __syncthreads();
        for (int k = 0; k < 8; ++k) sh[threadIdx.x + k * 256] += v[k];
        __syncthreads();
    }
    if (totalOut && blockIdx.x == 0 && threadIdx.x == 0)
        *totalOut = (nb > 0) ? sh[nb - 1] : (T)0;
    T add = (blockIdx.x == 0) ? (T)0 : sh[blockIdx.x - 1];
    int base = blockIdx.x * SCAN_TILE;
    int end = base + SCAN_TILE; if (end > n) end = n;
    for (int i = base + threadIdx.x; i < end; i += SCAN_BLOCK) out[i] += add;
}

// ---------------- pipeline ----------------
// Pass A: classify tets + per-block LDS histogram of crossing edges over
// bins (R2-proven; R6 showed the binned structure is load-bearing: direct
// global scatter = 64B write-allocate per 8B record = 285us). Zeroes bigCnt.
__global__ __launch_bounds__(256) void k_classify_hist(
    const int* tet, const float* sdf, u8* ti8, u64* tetPack,
    u32* blockHist, u32* bigCnt, int T, int NB, int gB) {
    if (blockIdx.x == 0 && threadIdx.x == 0) *bigCnt = 0;
    __shared__ u32 hist[BIN_VR];
    for (int i = threadIdx.x; i < NB; i += 256) hist[i] = 0;
    __syncthreads();
    int base = blockIdx.x * TETS_PER_BLOCK;
    for (int it = 0; it < TETS_PER_BLOCK / 256; ++it) {
        int t = base + it * 256 + threadIdx.x;
        if (t < T) {
            int4 q = reinterpret_cast<const int4*>(tet)[t];
            int ti = (sdf[q.x] > 0.0f ? 1 : 0) | (sdf[q.y] > 0.0f ? 2 : 0) |
                     (sdf[q.z] > 0.0f ? 4 : 0) | (sdf[q.w] > 0.0f ? 8 : 0);
            ti8[t] = (u8)ti;
            int nt = d_NUMTRI[ti];
            tetPack[t] = ((u64)(nt == 1 ? 1 : 0) << 21) | (u64)(nt == 2 ? 1 : 0);
            if (nt != 0) {
                int idx[4] = {q.x, q.y, q.z, q.w};
                #pragma unroll
                for (int e = 0; e < 6; ++e) {
                    int e0 = d_E0[e], e1 = d_E1[e];
                    if (((ti >> e0) ^ (ti >> e1)) & 1) {
                        int a = idx[e0], b = idx[e1];
                        int mn = a < b ? a : b;
                        atomicAdd(&hist[mn >> BIN_SHIFT], 1u);
                    }
                }
            }
        }
    }
    __syncthreads();
    for (int i = threadIdx.x; i < NB; i += 256)
        blockHist[(size_t)i * gB + blockIdx.x] = hist[i];
}

// Pass B: block-local LDS cursors hand out contiguous slots in the
// bin-sorted record array (writes are per-(bin,block) contiguous bursts).
// Records carry prov = 6*t + e for the direct idx_map scatter.
__global__ __launch_bounds__(256) void k_binfill(
    const int* tet, const u8* ti8, const u32* blockHistScan,
    u32* binData, u32* binProv, int T, int NB, int gB) {
    __shared__ u32 cur[BIN_VR];
    for (int i = threadIdx.x; i < NB; i += 256)
        cur[i] = blockHistScan[(size_t)i * gB + blockIdx.x];
    __syncthreads();
    int base = blockIdx.x * TETS_PER_BLOCK;
    for (int it = 0; it < TETS_PER_BLOCK / 256; ++it) {
        int t = base + it * 256 + threadIdx.x;
        if (t < T) {
            int ti = ti8[t];
            if (d_NUMTRI[ti] != 0) {
                int4 q = reinterpret_cast<const int4*>(tet)[t];
                int idx[4] = {q.x, q.y, q.z, q.w};
                #pragma unroll
                for (int e = 0; e < 6; ++e) {
                    int e0 = d_E0[e], e1 = d_E1[e];
                    if (((ti >> e0) ^ (ti >> e1)) & 1) {
                        int a = idx[e0], b = idx[e1];
                        int mn = a < b ? a : b;
                        int mx = a < b ? b : a;
                        u32 slot = atomicAdd(&cur[mn >> BIN_SHIFT], 1u);
                        binData[slot] = ((u32)(mn & (BIN_VR - 1)) << 18) | (u32)mx;
                        binProv[slot] = 6u * (u32)t + (u32)e;
                    }
                }
            }
        }
    }
}

// one block per bin: LDS histogram over the bin's records, then LDS scan of
// the 512 padded counts -> bucketCnt + WITHIN-BIN offsets (into bucketStart
// as temp) + per-bin padded total. Replaces bincount + the whole 3-dispatch
// padCnt scan chain.
__global__ __launch_bounds__(256) void k_bincount2(
    const u32* blockHistScan, const u32* totalPtr, const u32* binData,
    u32* bucketCnt, u32* bucketStart, u32* binTotals, int V, int NB, int gB) {
    int bin = blockIdx.x;
    __shared__ u32 hist[BIN_VR];
    __shared__ u32 sc[BIN_VR];
    for (int i = threadIdx.x; i < BIN_VR; i += 256) hist[i] = 0;
    __syncthreads();
    u32 s = blockHistScan[(size_t)bin * gB];
    u32 e = (bin + 1 < NB) ? blockHistScan[(size_t)(bin + 1) * gB] : *totalPtr;
    for (u32 i = s + threadIdx.x; i < e; i += 256)
        atomicAdd(&hist[binData[i] >> 18], 1u);
    __syncthreads();
    int t0 = threadIdx.x, t1 = threadIdx.x + 256;
    sc[t0] = (hist[t0] + 3u) & ~3u;          // pad4; empty buckets stay 0
    sc[t1] = (hist[t1] + 3u) & ~3u;
    __syncthreads();
    for (int off = 1; off < BIN_VR; off <<= 1) {
        u32 v0 = (t0 >= off) ? sc[t0 - off] : 0u;
        u32 v1 = (t1 >= off) ? sc[t1 - off] : 0u;
        __syncthreads();
        sc[t0] += v0; sc[t1] += v1;          // inclusive scan
        __syncthreads();
    }
    int vbase = bin << BIN_SHIFT;
    for (int i = threadIdx.x; i < BIN_VR; i += 256) {
        int v = vbase + i;
        if (v < V) {
            u32 h = hist[i];
            bucketCnt[v] = h;
            bucketStart[v] = sc[i] - ((h + 3u) & ~3u);   // local excl offset
        }
    }
    if (threadIdx.x == 0) binTotals[bin] = sc[BIN_VR - 1];
}

// one block per bin: redundant LDS scan of the <=512 bin totals -> binBase;
// finalize bucketStart (absolute), then scatter (mx,prov) uint2 records into
// the bin's L2-resident window via LDS cursors.
__global__ __launch_bounds__(256) void k_binscatter2(
    const u32* blockHistScan, const u32* totalPtr, const u32* binData,
    const u32* binProv, const u32* binTotals, u32* bucketStart, uint2* rec2,
    int V, int NB, int gB) {
    int bin = blockIdx.x;
    __shared__ u32 bt[BIN_VR];
    __shared__ u32 cur[BIN_VR];
    int t0 = threadIdx.x, t1 = threadIdx.x + 256;
    bt[t0] = (t0 < NB) ? binTotals[t0] : 0u;
    bt[t1] = (t1 < NB) ? binTotals[t1] : 0u;
    __syncthreads();
    for (int off = 1; off < BIN_VR; off <<= 1) {
        u32 v0 = (t0 >= off) ? bt[t0 - off] : 0u;
        u32 v1 = (t1 >= off) ? bt[t1 - off] : 0u;
        __syncthreads();
        bt[t0] += v0; bt[t1] += v1;
        __syncthreads();
    }
    u32 binBase = (bin == 0) ? 0u : bt[bin - 1];
    int vbase = bin << BIN_SHIFT;
    for (int i = threadIdx.x; i < BIN_VR; i += 256) {
        int v = vbase + i;
        if (v < V) {
            u32 a = binBase + bucketStart[v];
            bucketStart[v] = a;
            cur[i] = a;
        } else cur[i] = 0u;
    }
    __syncthreads();
    u32 s = blockHistScan[(size_t)bin * gB];
    u32 e = (bin + 1 < NB) ? blockHistScan[(size_t)(bin + 1) * gB] : *totalPtr;
    for (u32 i = s + threadIdx.x; i < e; i += 256) {
        u32 rec = binData[i];
        u32 pv = binProv[i];
        u32 slot = atomicAdd(&cur[rec >> 18], 1u);
        rec2[slot] = make_uint2(rec & 0x3FFFFu, pv);
    }
}

// HOT sort+dedup — R2's measured-best structure (93us): ONE bucket per
// 64-lane wave (wave-UNIFORM n -> SGPR loop; R5's 32-lane segments made n
// divergent and regressed to 134us), 4 buckets/256-block, zero LDS, no
// barriers. Plain idxmap stores (NT = uncached HBM RMW = R3 disaster).
__global__ __launch_bounds__(256) void k_sortdedup(
    const u32* bucketCnt, const u32* bucketStart, uint2* rec2,
    u32* idxmap, u32* crossCnt, u32* bigList, u32* bigCnt, int V)
{
    int v = blockIdx.x * 4 + (threadIdx.x >> 6);
    if (v >= V) return;
    int lane = threadIdx.x & 63;
    int n = (int)bucketCnt[v];
    if (n == 0) { if (lane == 0) crossCnt[v] = 0; return; }
    if (n > 64) {
        if (lane == 0) bigList[atomicAdd(bigCnt, 1u)] = (u32)v;
        return;
    }
    long long start = (long long)bucketStart[v];
    uint2 rp = (lane < n) ? rec2[start + lane] : make_uint2(0xFFFFFFFFu, 0u);
    u32 key = rp.x, prov = rp.y;
    int rank = 0;
    for (int j = 0; j < n; ++j) {               // wave-uniform bound, avg ~15
        u32 kj = (u32)__shfl((int)key, j);
        rank += (kj < key || (kj == key && j < lane)) ? 1 : 0;
    }
    u32 sorted = (u32)__builtin_amdgcn_ds_permute(rank << 2, (int)key);
    u32 prev = (u32)__shfl((int)sorted, lane - 1);
    bool nf = (lane < n) && (lane == 0 || prev != sorted);
    u64 m = __ballot(nf);
    int idx = __popcll(m & ((1ull << lane) - 1ull));
    if (nf) rec2[start + idx].x = sorted;
    int ldSorted = nf ? idx : idx - 1;          // dedup idx at sorted pos lane
    int ldOrig = __shfl(ldSorted, rank);        // my record sits at pos rank
    if (lane < n) idxmap[prov] = (u32)ldOrig;
    if (lane == 0) crossCnt[v] = (u32)__popcll(m);
}

// Overflow (64<n<=256, rare low-index buckets): full wave per bucket,
// register-chunked (4x64) two-pass shfl rank/dedup — no LDS, no serial work
// (R4 lesson: lane-0 insertion sort on real buckets = 207us tail). Serial
// remains only for n>256 (needs a vertex in ~85+ tets; P~0).
__global__ __launch_bounds__(256) void k_sortbig(
    const u32* bigList, const u32* bigCnt, const u32* bucketCnt,
    const u32* bucketStart, uint2* rec2, u32* idxmap, u32* crossCnt)
{
    int nbig = (int)*bigCnt;
    int lane = threadIdx.x & 63;
    int wave = (blockIdx.x << 2) + (threadIdx.x >> 6);
    int stride = gridDim.x << 2;
    for (int b = wave; b < nbig; b += stride) {
        int v = (int)bigList[b];
        int n = (int)bucketCnt[v];
        long long start = (long long)bucketStart[v];
        if (n <= 256) {
            int chunks = (n + 63) >> 6;         // 1..4
            u32 key[4], prov[4], kf[4];
            int myi[4];
            #pragma unroll
            for (int c = 0; c < 4; ++c) {
                myi[c] = (c << 6) + lane;
                key[c] = 0xFFFFFFFFu; prov[c] = 0u;
                if (c < chunks && myi[c] < n) {
                    uint2 rp = rec2[start + myi[c]];
                    key[c] = rp.x; prov[c] = rp.y;
                }
            }
            bool tie[4] = {false, false, false, false};
            #pragma unroll
            for (int c2 = 0; c2 < 4; ++c2) {
                if (c2 < chunks) {
                    int base2 = c2 << 6;
                    int lim = n - base2; if (lim > 64) lim = 64;
                    for (int j = 0; j < lim; ++j) {
                        u32 kj = (u32)__shfl((int)key[c2], j);
                        int jg = base2 + j;
                        #pragma unroll
                        for (int c = 0; c < 4; ++c) {
                            if (c < chunks)
                                tie[c] = tie[c] | (kj == key[c] && jg < myi[c]);
                        }
                    }
                }
            }
            u32 uq = 0;
            #pragma unroll
            for (int c = 0; c < 4; ++c) {
                bool isf = (c < chunks) && (myi[c] < n) && !tie[c];
                kf[c] = key[c] | (isf ? 0x80000000u : 0u);
                u64 bal = __ballot(isf);
                uq += (u32)__popcll(bal);
            }
            int uless[4] = {0, 0, 0, 0};
            #pragma unroll
            for (int c2 = 0; c2 < 4; ++c2) {
                if (c2 < chunks) {
                    int base2 = c2 << 6;
                    int lim = n - base2; if (lim > 64) lim = 64;
                    for (int j = 0; j < lim; ++j) {
                        u32 kfj = (u32)__shfl((int)kf[c2], j);
                        u32 kj = kfj & 0x7FFFFFFFu;
                        bool fj = (kfj & 0x80000000u) != 0u;
                        #pragma unroll
                        for (int c = 0; c < 4; ++c) {
                            if (c < chunks)
                                uless[c] += (fj && kj < key[c]) ? 1 : 0;
                        }
                    }
                }
            }
            #pragma unroll
            for (int c = 0; c < 4; ++c) {
                if (c < chunks && myi[c] < n) {
                    if (kf[c] & 0x80000000u)
                        rec2[start + uless[c]].x = key[c];
                    idxmap[prov[c]] = (u32)uless[c];
                }
            }
            if (lane == 0) crossCnt[v] = uq;
        } else if (lane == 0) {
            for (int i = 1; i < n; ++i) {
                uint2 kk = rec2[start + i];
                int j = i - 1;
                while (j >= 0 && rec2[start + j].x > kk.x) {
                    rec2[start + j + 1] = rec2[start + j]; --j;
                }
                rec2[start + j + 1] = kk;
            }
            int uc = 0; u32 prev = 0xFFFFFFFFu;
            for (int i = 0; i < n; ++i) {
                uint2 r = rec2[start + i];
                if (r.x != prev) { rec2[start + uc].x = r.x; ++uc; prev = r.x; }
                idxmap[r.y] = (u32)(uc - 1);
            }
            crossCnt[v] = (u32)uc;
        }
    }
}

// 32-lane segments, 8 buckets per 256-block; lane i -> unique crossing edge
// i -> vertex crossScan[v]+i. Strided loop handles u>32.
__global__ __launch_bounds__(256) void k_verts(
    const u32* crossCnt, const u32* bucketStart, const uint2* rec2, const u32* crossScan,
    const float* pos, const float* sdf, float* out, int V)
{
    int v = blockIdx.x * 8 + (threadIdx.x >> 5);
    if (v >= V) return;
    int slane = threadIdx.x & 31;
    int u = (int)crossCnt[v];
    if (u == 0) return;
    long long start = (long long)bucketStart[v];
    int cBase = (int)crossScan[v];
    float s0 = sdf[v];
    float p0x = pos[3 * v], p0y = pos[3 * v + 1], p0z = pos[3 * v + 2];
    for (int i = slane; i < u; i += 32) {
        int b = (int)rec2[start + i].x;
        long long k = cBase + i;
        float s1 = sdf[b];
        float d = s0 - s1;
        float w0 = -s1 / d, w1 = s0 / d;
        out[3 * k + 0] = p0x * w0 + pos[3 * b + 0] * w1;
        out[3 * k + 1] = p0y * w0 + pos[3 * b + 1] * w1;
        out[3 * k + 2] = p0z * w0 + pos[3 * b + 2] * w1;
    }
}

// faces + uv_idx. Edge->vertex id is a direct read: idx_map[6t+e] holds the
// local dedup index within bucket(a); global id = crossScan[a] + local.
__global__ void k_faces(const int* tet, const u8* ti8, const u64* tetScan,
                        const u32* idxmap, const u32* crossScan,
                        const u64* meta0, const u32* NePtr,
                        float* out, int T, int Ngrid, long long uvFloats)
{
    int t = blockIdx.x * 256 + threadIdx.x;
    if (t >= T) return;
    int ti = ti8[t];
    int nt = d_NUMTRI[ti];
    if (nt == 0) return;

    u64 tot = *meta0;
    int C1 = (int)((tot >> 21) & 0x1fffffull);
    int C2 = (int)(tot & 0x1fffffull);
    int Ne = (int)*NePtr;
    long long facesBase = 3LL * Ne;
    long long F = (long long)C1 + 2LL * C2;
    long long uvIdxBase = facesBase + 3LL * F + uvFloats;

    int4 q = reinterpret_cast<const int4*>(tet)[t];
    int idx[4] = {q.x, q.y, q.z, q.w};
    const uint2* imp = reinterpret_cast<const uint2*>(idxmap + 6ll * t);
    uint2 r0 = imp[0], r1 = imp[1], r2 = imp[2];
    u32 im[6] = {r0.x, r0.y, r1.x, r1.y, r2.x, r2.y};
    const int* row = d_TRI[ti];

    int emap[6];
    unsigned done = 0;
    float fv[6];
    #pragma unroll
    for (int j = 0; j < 6; ++j) {
        if (j >= 3 * nt) break;
        int e = row[j];
        if (!((done >> e) & 1)) {
            done |= 1u << e;
            int a = idx[d_E0[e]], b = idx[d_E1[e]];
            if (b < a) a = b;                  // a = min endpoint = bucket
            emap[e] = (int)crossScan[a] + (int)im[e];
        }
        fv[j] = (float)emap[e];
    }

    u64 sc = tetScan[t];
    int r1s = (int)((sc >> 21) & 0x1fffffull);
    int r2s = (int)(sc & 0x1fffffull);
    int tet_idx = (t / Ngrid) * Ngrid + (t % Ngrid);

    if (nt == 1) {
        long long f = r1s;
        out[facesBase + 3 * f + 0] = fv[0];
        out[facesBase + 3 * f + 1] = fv[1];
        out[facesBase + 3 * f + 2] = fv[2];
        out[uvIdxBase + 3 * f + 0] = (float)(4 * tet_idx);
        out[uvIdxBase + 3 * f + 1] = (float)(4 * tet_idx + 1);
        out[uvIdxBase + 3 * f + 2] = (float)(4 * tet_idx + 2);
    } else {
        long long f0 = (long long)C1 + 2LL * r2s;
        out[facesBase + 3 * f0 + 0] = fv[0];
        out[facesBase + 3 * f0 + 1] = fv[1];
        out[facesBase + 3 * f0 + 2] = fv[2];
        out[facesBase + 3 * (f0 + 1) + 0] = fv[3];
        out[facesBase + 3 * (f0 + 1) + 1] = fv[4];
        out[facesBase + 3 * (f0 + 1) + 2] = fv[5];
        out[uvIdxBase + 3 * f0 + 0] = (float)(4 * tet_idx);
        out[uvIdxBase + 3 * f0 + 1] = (float)(4 * tet_idx + 1);
        out[uvIdxBase + 3 * f0 + 2] = (float)(4 * tet_idx + 2);
        out[uvIdxBase + 3 * (f0 + 1) + 0] = (float)(4 * tet_idx);
        out[uvIdxBase + 3 * (f0 + 1) + 1] = (float)(4 * tet_idx + 2);
        out[uvIdxBase + 3 * (f0 + 1) + 2] = (float)(4 * tet_idx + 3);
    }
}

__global__ void k_uvs(float* out, const u64* meta0, const u32* NePtr, int Ngrid) {
    int c = blockIdx.x * 256 + threadIdx.x;
    int total = Ngrid * Ngrid;
    if (c >= total) return;
    u64 tot = *meta0;
    int C1 = (int)((tot >> 21) & 0x1fffffull);
    int C2 = (int)(tot & 0x1fffffull);
    int Ne = (int)*NePtr;
    long long uvBase = 3LL * Ne + 3LL * ((long long)C1 + 2LL * C2);
    int i = c / Ngrid, j = c % Ngrid;
    double step = (Ngrid > 1) ? (1.0 - 1.0 / (double)Ngrid) / (double)(Ngrid - 1) : 0.0;
    float x = (float)((double)j * step);
    float y = (float)((double)i * step);
    float pad = (float)(0.9 / (double)Ngrid);
    long long o = uvBase + 8LL * c;
    out[o + 0] = x;       out[o + 1] = y;
    out[o + 2] = x + pad; out[o + 3] = y;
    out[o + 4] = x + pad; out[o + 5] = y + pad;
    out[o + 6] = x;       out[o + 7] = y + pad;
}

// ---------------- host ----------------
template <typename T>
static void run_scan2(const T* in, T* out, int n, T* blockSums, T* totalOut,
                      hipStream_t stream) {
    int nb = (n + SCAN_TILE - 1) / SCAN_TILE;
    scanA_t<T><<<nb, SCAN_BLOCK, 0, stream>>>(in, out, n, blockSums);
    scanCf_t<T><<<nb, SCAN_BLOCK, 0, stream>>>(out, n, blockSums, nb, totalOut);
}

extern "C" void kernel_launch(void* const* d_in, const int* in_sizes, int n_in,
                              void* d_out, int out_size, void* d_ws, size_t ws_size,
                              hipStream_t stream) {
    const float* pos = (const float*)d_in[0];
    const float* sdf = (const float*)d_in[1];
    const int* tet = (const int*)d_in[2];
    int V = in_sizes[1];
    int T = in_sizes[2] / 4;
    float* out = (float*)d_out;

    int NB = (V + BIN_VR - 1) / BIN_VR;
    int gB = (T + TETS_PER_BLOCK - 1) / TETS_PER_BLOCK;
    int nHist = NB * gB;

    char* p = (char*)d_ws;
    auto alloc = [&](size_t bytes) -> void* {
        void* r = (void*)p;
        p += (bytes + 255) & ~(size_t)255;
        return r;
    };
    u8*  ti8           = (u8*) alloc((size_t)T);
    u64* tetPack       = (u64*)alloc((size_t)T * 8);
    u64* tetScan       = (u64*)alloc((size_t)T * 8);
    u32* blockHist     = (u32*)alloc((size_t)nHist * 4);
    u32* blockHistScan = (u32*)alloc((size_t)nHist * 4);
    u32* binData       = (u32*)alloc((size_t)6 * T * 4);   // reused as idxmap
    u32* binProv       = (u32*)alloc((size_t)6 * T * 4);
    u32* bucketCnt     = (u32*)alloc((size_t)V * 4);
    u32* bucketStart   = (u32*)alloc((size_t)V * 4);
    u32* binTotals     = (u32*)alloc((size_t)BIN_VR * 4);
    u32* crossCnt      = (u32*)alloc((size_t)V * 4);
    u32* crossScan     = (u32*)alloc((size_t)V * 4);
    uint2* rec2        = (uint2*)alloc(((size_t)6 * T + 4 * (size_t)V) * 8);
    u32* bigList       = (u32*)alloc((size_t)V * 4);
    u64* blockSums64   = (u64*)alloc(2048 * 8);
    u32* blockSums32   = (u32*)alloc(2048 * 4);
    u64* meta64        = (u64*)alloc(8 * 8);
    u32* NePtr         = (u32*)(meta64 + 4);
    u32* NeInstPtr     = (u32*)(meta64 + 5);
    u32* bigCnt        = (u32*)(meta64 + 6);

    // idxmap aliases binData: binData's last reader is k_binscatter2,
    // idxmap's first writer is k_sortdedup (strictly after). 6T u32 exactly.
    u32* idxmap = binData;

    long long M = (2LL * T + 1) / 2;
    int Ngrid = (int)std::sqrt((double)M);
    while ((long long)Ngrid * Ngrid < M) ++Ngrid;
    if (Ngrid < 1) Ngrid = 1;
    long long uvFloats = 8LL * Ngrid * Ngrid;

    int gT = (T + 255) / 256;
    int gV4 = (V + 3) / 4;
    int gV8 = (V + 7) / 8;

    k_classify_hist<<<gB, 256, 0, stream>>>(tet, sdf, ti8, tetPack, blockHist,
                                            bigCnt, T, NB, gB);
    run_scan2<u64>(tetPack, tetScan, T, blockSums64, meta64, stream);
    run_scan2<u32>(blockHist, blockHistScan, nHist, blockSums32, NeInstPtr, stream);
    k_binfill<<<gB, 256, 0, stream>>>(tet, ti8, blockHistScan, binData, binProv,
                                      T, NB, gB);
    k_bincount2<<<NB, 256, 0, stream>>>(blockHistScan, NeInstPtr, binData,
                                        bucketCnt, bucketStart, binTotals,
                                        V, NB, gB);
    k_binscatter2<<<NB, 256, 0, stream>>>(blockHistScan, NeInstPtr, binData,
                                          binProv, binTotals, bucketStart,
                                          rec2, V, NB, gB);
    k_sortdedup<<<gV4, 256, 0, stream>>>(bucketCnt, bucketStart, rec2,
                                         idxmap, crossCnt, bigList, bigCnt, V);
    k_sortbig<<<1024, 256, 0, stream>>>(bigList, bigCnt, bucketCnt, bucketStart,
                                        rec2, idxmap, crossCnt);
    run_scan2<u32>(crossCnt, crossScan, V, blockSums32, NePtr, stream);
    k_verts<<<gV8, 256, 0, stream>>>(crossCnt, bucketStart, rec2, crossScan,
                                     pos, sdf, out, V);
    k_faces<<<gT, 256, 0, stream>>>(tet, ti8, tetScan, idxmap, crossScan,
                                    meta64, NePtr, out, T, Ngrid, uvFloats);
    int gUV = (Ngrid * Ngrid + 255) / 256;
    k_uvs<<<gUV, 256, 0, stream>>>(out, meta64, NePtr, Ngrid);
}

// Round 8
// 451.643 us; speedup vs baseline: 1.6310x; 1.0177x over previous
//
#include <hip/hip_runtime.h>
#include <cmath>

typedef unsigned long long u64;
typedef unsigned int u32;
typedef unsigned char u8;

#define SCAN_BLOCK 256
#define SCAN_ELEMS 8
#define SCAN_TILE (SCAN_BLOCK * SCAN_ELEMS)

// counting-sort bins: 512 vertices per bin (V=200000 -> NB=391 <= 512).
// record packing (mn&511)<<18 | mx requires V <= 2^18.
#define BIN_SHIFT 9
#define BIN_VR 512
#define TETS_PER_BLOCK 2048

__constant__ int d_NUMTRI[16] = {0,1,1,2,1,2,2,1,1,2,2,1,2,1,1,0};
__constant__ int d_TRI[16][6] = {
 {-1,-1,-1,-1,-1,-1},{1,0,2,-1,-1,-1},{4,0,3,-1,-1,-1},{1,4,2,1,3,4},
 {3,1,5,-1,-1,-1},{2,3,0,2,5,3},{1,4,0,1,5,4},{4,2,5,-1,-1,-1},
 {4,5,2,-1,-1,-1},{4,1,0,4,5,1},{3,2,0,3,5,2},{1,3,5,-1,-1,-1},
 {4,1,2,4,3,1},{3,0,4,-1,-1,-1},{2,0,1,-1,-1,-1},{-1,-1,-1,-1,-1,-1}};
__constant__ int d_E0[6] = {0,0,0,1,1,2};
__constant__ int d_E1[6] = {1,2,3,2,3,3};

// ---------------- exclusive scan (2-dispatch: scanA + fused scanCf) --------
// NOTE: tet m1/m2 scan MUST be u64 — running m1 total needs 19 bits packed at
// bit 21 (overflowed u32 in an early round).
template <typename T>
__global__ void scanA_t(const T* in, T* out, int n, T* blockSums) {
    __shared__ T tsum[SCAN_BLOCK];
    int tbase = blockIdx.x * SCAN_TILE + threadIdx.x * SCAN_ELEMS;
    T vals[SCAN_ELEMS];
    T run = 0;
    for (int k = 0; k < SCAN_ELEMS; ++k) {
        int i = tbase + k;
        T v = (i < n) ? in[i] : (T)0;
        vals[k] = run;
        run += v;
    }
    tsum[threadIdx.x] = run;
    __syncthreads();
    for (int off = 1; off < SCAN_BLOCK; off <<= 1) {
        T v = (threadIdx.x >= (unsigned)off) ? tsum[threadIdx.x - off] : (T)0;
        __syncthreads();
        tsum[threadIdx.x] += v;
        __syncthreads();
    }
    T texcl = (threadIdx.x == 0) ? (T)0 : tsum[threadIdx.x - 1];
    for (int k = 0; k < SCAN_ELEMS; ++k) {
        int i = tbase + k;
        if (i < n) out[i] = texcl + vals[k];
    }
    if (threadIdx.x == SCAN_BLOCK - 1) blockSums[blockIdx.x] = tsum[SCAN_BLOCK - 1];
}

// Fused scanB+scanC: every block redundantly scans the <=2048 blockSums in
// LDS (<=16KB read, L2-hit) and adds its exclusive prefix. Kills the
// 1-block scanB dispatch per chain. Block 0 also emits the grand total.
template <typename T>
__global__ void scanCf_t(T* out, int n, const T* bs, int nb, T* totalOut) {
    __shared__ T sh[2048];
    for (int i = threadIdx.x; i < 2048; i += 256) sh[i] = (i < nb) ? bs[i] : (T)0;
    __syncthreads();
    for (int off = 1; off < 2048; off <<= 1) {
        T v[8];
        for (int k = 0; k < 8; ++k) {
            int i = threadIdx.x + k * 256;
            v[k] = (i >= off) ? sh[i - off] : (T)0;
        }
        __syncthreads();
        for (int k = 0; k < 8; ++k) sh[threadIdx.x + k * 256] += v[k];
        __syncthreads();
    }
    if (totalOut && blockIdx.x == 0 && threadIdx.x == 0)
        *totalOut = (nb > 0) ? sh[nb - 1] : (T)0;
    T add = (blockIdx.x == 0) ? (T)0 : sh[blockIdx.x - 1];
    int base = blockIdx.x * SCAN_TILE;
    int end = base + SCAN_TILE; if (end > n) end = n;
    for (int i = base + threadIdx.x; i < end; i += SCAN_BLOCK) out[i] += add;
}

// ---------------- pipeline ----------------
// Pass A: classify tets + per-block LDS histogram of crossing edges over
// bins (binned structure is load-bearing: R6's direct global scatter = 64B
// write-allocate per 8B record = 285us). Zeroes bigCnt.
__global__ __launch_bounds__(256) void k_classify_hist(
    const int* tet, const float* sdf, u8* ti8, u64* tetPack,
    u32* blockHist, u32* bigCnt, int T, int NB, int gB) {
    if (blockIdx.x == 0 && threadIdx.x == 0) *bigCnt = 0;
    __shared__ u32 hist[BIN_VR];
    for (int i = threadIdx.x; i < NB; i += 256) hist[i] = 0;
    __syncthreads();
    int base = blockIdx.x * TETS_PER_BLOCK;
    for (int it = 0; it < TETS_PER_BLOCK / 256; ++it) {
        int t = base + it * 256 + threadIdx.x;
        if (t < T) {
            int4 q = reinterpret_cast<const int4*>(tet)[t];
            int ti = (sdf[q.x] > 0.0f ? 1 : 0) | (sdf[q.y] > 0.0f ? 2 : 0) |
                     (sdf[q.z] > 0.0f ? 4 : 0) | (sdf[q.w] > 0.0f ? 8 : 0);
            ti8[t] = (u8)ti;
            int nt = d_NUMTRI[ti];
            tetPack[t] = ((u64)(nt == 1 ? 1 : 0) << 21) | (u64)(nt == 2 ? 1 : 0);
            if (nt != 0) {
                int idx[4] = {q.x, q.y, q.z, q.w};
                #pragma unroll
                for (int e = 0; e < 6; ++e) {
                    int e0 = d_E0[e], e1 = d_E1[e];
                    if (((ti >> e0) ^ (ti >> e1)) & 1) {
                        int a = idx[e0], b = idx[e1];
                        int mn = a < b ? a : b;
                        atomicAdd(&hist[mn >> BIN_SHIFT], 1u);
                    }
                }
            }
        }
    }
    __syncthreads();
    for (int i = threadIdx.x; i < NB; i += 256)
        blockHist[(size_t)i * gB + blockIdx.x] = hist[i];
}

// Pass B: block-local LDS cursors hand out contiguous slots in the
// bin-sorted record array. Records carry prov = 6*t + e.
__global__ __launch_bounds__(256) void k_binfill(
    const int* tet, const u8* ti8, const u32* blockHistScan,
    u32* binData, u32* binProv, int T, int NB, int gB) {
    __shared__ u32 cur[BIN_VR];
    for (int i = threadIdx.x; i < NB; i += 256)
        cur[i] = blockHistScan[(size_t)i * gB + blockIdx.x];
    __syncthreads();
    int base = blockIdx.x * TETS_PER_BLOCK;
    for (int it = 0; it < TETS_PER_BLOCK / 256; ++it) {
        int t = base + it * 256 + threadIdx.x;
        if (t < T) {
            int ti = ti8[t];
            if (d_NUMTRI[ti] != 0) {
                int4 q = reinterpret_cast<const int4*>(tet)[t];
                int idx[4] = {q.x, q.y, q.z, q.w};
                #pragma unroll
                for (int e = 0; e < 6; ++e) {
                    int e0 = d_E0[e], e1 = d_E1[e];
                    if (((ti >> e0) ^ (ti >> e1)) & 1) {
                        int a = idx[e0], b = idx[e1];
                        int mn = a < b ? a : b;
                        int mx = a < b ? b : a;
                        u32 slot = atomicAdd(&cur[mn >> BIN_SHIFT], 1u);
                        binData[slot] = ((u32)(mn & (BIN_VR - 1)) << 18) | (u32)mx;
                        binProv[slot] = 6u * (u32)t + (u32)e;
                    }
                }
            }
        }
    }
}

// one block per bin: LDS histogram over the bin's records, then LDS scan of
// the 512 padded counts -> bucketCnt + within-bin offsets + per-bin total.
__global__ __launch_bounds__(256) void k_bincount2(
    const u32* blockHistScan, const u32* totalPtr, const u32* binData,
    u32* bucketCnt, u32* bucketStart, u32* binTotals, int V, int NB, int gB) {
    int bin = blockIdx.x;
    __shared__ u32 hist[BIN_VR];
    __shared__ u32 sc[BIN_VR];
    for (int i = threadIdx.x; i < BIN_VR; i += 256) hist[i] = 0;
    __syncthreads();
    u32 s = blockHistScan[(size_t)bin * gB];
    u32 e = (bin + 1 < NB) ? blockHistScan[(size_t)(bin + 1) * gB] : *totalPtr;
    for (u32 i = s + threadIdx.x; i < e; i += 256)
        atomicAdd(&hist[binData[i] >> 18], 1u);
    __syncthreads();
    int t0 = threadIdx.x, t1 = threadIdx.x + 256;
    sc[t0] = (hist[t0] + 3u) & ~3u;          // pad4; empty buckets stay 0
    sc[t1] = (hist[t1] + 3u) & ~3u;
    __syncthreads();
    for (int off = 1; off < BIN_VR; off <<= 1) {
        u32 v0 = (t0 >= off) ? sc[t0 - off] : 0u;
        u32 v1 = (t1 >= off) ? sc[t1 - off] : 0u;
        __syncthreads();
        sc[t0] += v0; sc[t1] += v1;          // inclusive scan
        __syncthreads();
    }
    int vbase = bin << BIN_SHIFT;
    for (int i = threadIdx.x; i < BIN_VR; i += 256) {
        int v = vbase + i;
        if (v < V) {
            u32 h = hist[i];
            bucketCnt[v] = h;
            bucketStart[v] = sc[i] - ((h + 3u) & ~3u);   // local excl offset
        }
    }
    if (threadIdx.x == 0) binTotals[bin] = sc[BIN_VR - 1];
}

// one block per bin: redundant LDS scan of the <=512 bin totals -> binBase;
// finalize bucketStart (absolute), then scatter (mx,prov) uint2 records into
// the bin's L2-resident window via LDS cursors.
__global__ __launch_bounds__(256) void k_binscatter2(
    const u32* blockHistScan, const u32* totalPtr, const u32* binData,
    const u32* binProv, const u32* binTotals, u32* bucketStart, uint2* rec2,
    int V, int NB, int gB) {
    int bin = blockIdx.x;
    __shared__ u32 bt[BIN_VR];
    __shared__ u32 cur[BIN_VR];
    int t0 = threadIdx.x, t1 = threadIdx.x + 256;
    bt[t0] = (t0 < NB) ? binTotals[t0] : 0u;
    bt[t1] = (t1 < NB) ? binTotals[t1] : 0u;
    __syncthreads();
    for (int off = 1; off < BIN_VR; off <<= 1) {
        u32 v0 = (t0 >= off) ? bt[t0 - off] : 0u;
        u32 v1 = (t1 >= off) ? bt[t1 - off] : 0u;
        __syncthreads();
        bt[t0] += v0; bt[t1] += v1;
        __syncthreads();
    }
    u32 binBase = (bin == 0) ? 0u : bt[bin - 1];
    int vbase = bin << BIN_SHIFT;
    for (int i = threadIdx.x; i < BIN_VR; i += 256) {
        int v = vbase + i;
        if (v < V) {
            u32 a = binBase + bucketStart[v];
            bucketStart[v] = a;
            cur[i] = a;
        } else cur[i] = 0u;
    }
    __syncthreads();
    u32 s = blockHistScan[(size_t)bin * gB];
    u32 e = (bin + 1 < NB) ? blockHistScan[(size_t)(bin + 1) * gB] : *totalPtr;
    for (u32 i = s + threadIdx.x; i < e; i += 256) {
        u32 rec = binData[i];
        u32 pv = binProv[i];
        u32 slot = atomicAdd(&cur[rec >> 18], 1u);
        rec2[slot] = make_uint2(rec & 0x3FFFFu, pv);
    }
}

// HOT sort+dedup — R2/R7 measured-best structure: ONE bucket per 64-lane
// wave (wave-UNIFORM n -> SGPR loop; 32-lane segments made n divergent and
// regressed), 4 buckets/256-block, zero LDS, no barriers.
// idxmap is now u8 (dedup idx < 256 always): 6MB array vs 24MB u32 —
// R7 counters showed 21MB FETCH + ~80MB of the 102MB WRITE was line-thrash
// on the 24MB scatter target (per-XCD L2 = 4MB). Byte stores use HW byte
// enables; every prov is unique so no same-byte races.
__global__ __launch_bounds__(256) void k_sortdedup(
    const u32* bucketCnt, const u32* bucketStart, uint2* rec2,
    u8* idxmap, u32* crossCnt, u32* bigList, u32* bigCnt, int V)
{
    int v = blockIdx.x * 4 + (threadIdx.x >> 6);
    if (v >= V) return;
    int lane = threadIdx.x & 63;
    int n = (int)bucketCnt[v];
    if (n == 0) { if (lane == 0) crossCnt[v] = 0; return; }
    if (n > 64) {
        if (lane == 0) bigList[atomicAdd(bigCnt, 1u)] = (u32)v;
        return;
    }
    long long start = (long long)bucketStart[v];
    uint2 rp = (lane < n) ? rec2[start + lane] : make_uint2(0xFFFFFFFFu, 0u);
    u32 key = rp.x, prov = rp.y;
    int rank = 0;
    for (int j = 0; j < n; ++j) {               // wave-uniform bound, avg ~15
        u32 kj = (u32)__shfl((int)key, j);
        rank += (kj < key || (kj == key && j < lane)) ? 1 : 0;
    }
    u32 sorted = (u32)__builtin_amdgcn_ds_permute(rank << 2, (int)key);
    u32 prev = (u32)__shfl((int)sorted, lane - 1);
    bool nf = (lane < n) && (lane == 0 || prev != sorted);
    u64 m = __ballot(nf);
    int idx = __popcll(m & ((1ull << lane) - 1ull));
    if (nf) rec2[start + idx].x = sorted;
    int ldSorted = nf ? idx : idx - 1;          // dedup idx at sorted pos lane
    int ldOrig = __shfl(ldSorted, rank);        // my record sits at pos rank
    if (lane < n) idxmap[prov] = (u8)ldOrig;
    if (lane == 0) crossCnt[v] = (u32)__popcll(m);
}

// Overflow (64<n<=256, rare low-index buckets): full wave per bucket,
// register-chunked (4x64) two-pass shfl rank/dedup — no LDS, no serial work
// (R4 lesson: lane-0 insertion sort on real buckets = 207us tail). Serial
// remains only for n>256 (needs a vertex in ~85+ tets; P~0).
__global__ __launch_bounds__(256) void k_sortbig(
    const u32* bigList, const u32* bigCnt, const u32* bucketCnt,
    const u32* bucketStart, uint2* rec2, u8* idxmap, u32* crossCnt)
{
    int nbig = (int)*bigCnt;
    int lane = threadIdx.x & 63;
    int wave = (blockIdx.x << 2) + (threadIdx.x >> 6);
    int stride = gridDim.x << 2;
    for (int b = wave; b < nbig; b += stride) {
        int v = (int)bigList[b];
        int n = (int)bucketCnt[v];
        long long start = (long long)bucketStart[v];
        if (n <= 256) {
            int chunks = (n + 63) >> 6;         // 1..4
            u32 key[4], prov[4], kf[4];
            int myi[4];
            #pragma unroll
            for (int c = 0; c < 4; ++c) {
                myi[c] = (c << 6) + lane;
                key[c] = 0xFFFFFFFFu; prov[c] = 0u;
                if (c < chunks && myi[c] < n) {
                    uint2 rp = rec2[start + myi[c]];
                    key[c] = rp.x; prov[c] = rp.y;
                }
            }
            bool tie[4] = {false, false, false, false};
            #pragma unroll
            for (int c2 = 0; c2 < 4; ++c2) {
                if (c2 < chunks) {
                    int base2 = c2 << 6;
                    int lim = n - base2; if (lim > 64) lim = 64;
                    for (int j = 0; j < lim; ++j) {
                        u32 kj = (u32)__shfl((int)key[c2], j);
                        int jg = base2 + j;
                        #pragma unroll
                        for (int c = 0; c < 4; ++c) {
                            if (c < chunks)
                                tie[c] = tie[c] | (kj == key[c] && jg < myi[c]);
                        }
                    }
                }
            }
            u32 uq = 0;
            #pragma unroll
            for (int c = 0; c < 4; ++c) {
                bool isf = (c < chunks) && (myi[c] < n) && !tie[c];
                kf[c] = key[c] | (isf ? 0x80000000u : 0u);
                u64 bal = __ballot(isf);
                uq += (u32)__popcll(bal);
            }
            int uless[4] = {0, 0, 0, 0};
            #pragma unroll
            for (int c2 = 0; c2 < 4; ++c2) {
                if (c2 < chunks) {
                    int base2 = c2 << 6;
                    int lim = n - base2; if (lim > 64) lim = 64;
                    for (int j = 0; j < lim; ++j) {
                        u32 kfj = (u32)__shfl((int)kf[c2], j);
                        u32 kj = kfj & 0x7FFFFFFFu;
                        bool fj = (kfj & 0x80000000u) != 0u;
                        #pragma unroll
                        for (int c = 0; c < 4; ++c) {
                            if (c < chunks)
                                uless[c] += (fj && kj < key[c]) ? 1 : 0;
                        }
                    }
                }
            }
            #pragma unroll
            for (int c = 0; c < 4; ++c) {
                if (c < chunks && myi[c] < n) {
                    if (kf[c] & 0x80000000u)
                        rec2[start + uless[c]].x = key[c];
                    idxmap[prov[c]] = (u8)uless[c];
                }
            }
            if (lane == 0) crossCnt[v] = uq;
        } else if (lane == 0) {
            for (int i = 1; i < n; ++i) {
                uint2 kk = rec2[start + i];
                int j = i - 1;
                while (j >= 0 && rec2[start + j].x > kk.x) {
                    rec2[start + j + 1] = rec2[start + j]; --j;
                }
                rec2[start + j + 1] = kk;
            }
            int uc = 0; u32 prev = 0xFFFFFFFFu;
            for (int i = 0; i < n; ++i) {
                uint2 r = rec2[start + i];
                if (r.x != prev) { rec2[start + uc].x = r.x; ++uc; prev = r.x; }
                idxmap[r.y] = (u8)(uc - 1);
            }
            crossCnt[v] = (u32)uc;
        }
    }
}

// 32-lane segments, 8 buckets per 256-block; lane i -> unique crossing edge
// i -> vertex crossScan[v]+i. Strided loop handles u>32.
__global__ __launch_bounds__(256) void k_verts(
    const u32* crossCnt, const u32* bucketStart, const uint2* rec2, const u32* crossScan,
    const float* pos, const float* sdf, float* out, int V)
{
    int v = blockIdx.x * 8 + (threadIdx.x >> 5);
    if (v >= V) return;
    int slane = threadIdx.x & 31;
    int u = (int)crossCnt[v];
    if (u == 0) return;
    long long start = (long long)bucketStart[v];
    int cBase = (int)crossScan[v];
    float s0 = sdf[v];
    float p0x = pos[3 * v], p0y = pos[3 * v + 1], p0z = pos[3 * v + 2];
    for (int i = slane; i < u; i += 32) {
        int b = (int)rec2[start + i].x;
        long long k = cBase + i;
        float s1 = sdf[b];
        float d = s0 - s1;
        float w0 = -s1 / d, w1 = s0 / d;
        out[3 * k + 0] = p0x * w0 + pos[3 * b + 0] * w1;
        out[3 * k + 1] = p0y * w0 + pos[3 * b + 1] * w1;
        out[3 * k + 2] = p0z * w0 + pos[3 * b + 2] * w1;
    }
}

// faces + uv_idx + FUSED uv grid (Ngrid^2 >= T always since M == T, so the
// same grid covers both; saves the separate k_uvs dispatch). Edge->vertex id
// is a direct read: u8 idx_map[6t+e] holds the local dedup index within
// bucket(a); global id = crossScan[a] + local.
__global__ void k_faces(const int* tet, const u8* ti8, const u64* tetScan,
                        const u8* idxmap, const u32* crossScan,
                        const u64* meta0, const u32* NePtr,
                        float* out, int T, int Ngrid, long long uvFloats)
{
    int t = blockIdx.x * 256 + threadIdx.x;
    int uvTotal = Ngrid * Ngrid;
    if (t >= T && t >= uvTotal) return;

    u64 tot = *meta0;
    int C1 = (int)((tot >> 21) & 0x1fffffull);
    int C2 = (int)(tot & 0x1fffffull);
    int Ne = (int)*NePtr;
    long long facesBase = 3LL * Ne;
    long long F = (long long)C1 + 2LL * C2;
    long long uvBase = facesBase + 3LL * F;
    long long uvIdxBase = uvBase + uvFloats;

    if (t < uvTotal) {          // fused uv-grid write (was k_uvs)
        int i = t / Ngrid, j = t % Ngrid;
        double step = (Ngrid > 1) ? (1.0 - 1.0 / (double)Ngrid) / (double)(Ngrid - 1) : 0.0;
        float x = (float)((double)j * step);
        float y = (float)((double)i * step);
        float pad = (float)(0.9 / (double)Ngrid);
        long long o = uvBase + 8LL * t;
        out[o + 0] = x;       out[o + 1] = y;
        out[o + 2] = x + pad; out[o + 3] = y;
        out[o + 4] = x + pad; out[o + 5] = y + pad;
        out[o + 6] = x;       out[o + 7] = y + pad;
    }
    if (t >= T) return;

    int ti = ti8[t];
    int nt = d_NUMTRI[ti];
    if (nt == 0) return;

    int4 q = reinterpret_cast<const int4*>(tet)[t];
    int idx[4] = {q.x, q.y, q.z, q.w};
    // u8 idxmap row: 6 bytes at offset 6t (even -> u16-aligned)
    const unsigned short* imp =
        reinterpret_cast<const unsigned short*>(idxmap + 6ll * t);
    unsigned short w0 = imp[0], w1 = imp[1], w2 = imp[2];
    u32 im[6] = {(u32)(w0 & 0xFF), (u32)(w0 >> 8),
                 (u32)(w1 & 0xFF), (u32)(w1 >> 8),
                 (u32)(w2 & 0xFF), (u32)(w2 >> 8)};
    const int* row = d_TRI[ti];

    int emap[6];
    unsigned done = 0;
    float fv[6];
    #pragma unroll
    for (int j = 0; j < 6; ++j) {
        if (j >= 3 * nt) break;
        int e = row[j];
        if (!((done >> e) & 1)) {
            done |= 1u << e;
            int a = idx[d_E0[e]], b = idx[d_E1[e]];
            if (b < a) a = b;                  // a = min endpoint = bucket
            emap[e] = (int)crossScan[a] + (int)im[e];
        }
        fv[j] = (float)emap[e];
    }

    u64 sc = tetScan[t];
    int r1s = (int)((sc >> 21) & 0x1fffffull);
    int r2s = (int)(sc & 0x1fffffull);
    int tet_idx = (t / Ngrid) * Ngrid + (t % Ngrid);

    if (nt == 1) {
        long long f = r1s;
        out[facesBase + 3 * f + 0] = fv[0];
        out[facesBase + 3 * f + 1] = fv[1];
        out[facesBase + 3 * f + 2] = fv[2];
        out[uvIdxBase + 3 * f + 0] = (float)(4 * tet_idx);
        out[uvIdxBase + 3 * f + 1] = (float)(4 * tet_idx + 1);
        out[uvIdxBase + 3 * f + 2] = (float)(4 * tet_idx + 2);
    } else {
        long long f0 = (long long)C1 + 2LL * r2s;
        out[facesBase + 3 * f0 + 0] = fv[0];
        out[facesBase + 3 * f0 + 1] = fv[1];
        out[facesBase + 3 * f0 + 2] = fv[2];
        out[facesBase + 3 * (f0 + 1) + 0] = fv[3];
        out[facesBase + 3 * (f0 + 1) + 1] = fv[4];
        out[facesBase + 3 * (f0 + 1) + 2] = fv[5];
        out[uvIdxBase + 3 * f0 + 0] = (float)(4 * tet_idx);
        out[uvIdxBase + 3 * f0 + 1] = (float)(4 * tet_idx + 1);
        out[uvIdxBase + 3 * f0 + 2] = (float)(4 * tet_idx + 2);
        out[uvIdxBase + 3 * (f0 + 1) + 0] = (float)(4 * tet_idx);
        out[uvIdxBase + 3 * (f0 + 1) + 1] = (float)(4 * tet_idx + 2);
        out[uvIdxBase + 3 * (f0 + 1) + 2] = (float)(4 * tet_idx + 3);
    }
}

// ---------------- host ----------------
template <typename T>
static void run_scan2(const T* in, T* out, int n, T* blockSums, T* totalOut,
                      hipStream_t stream) {
    int nb = (n + SCAN_TILE - 1) / SCAN_TILE;
    scanA_t<T><<<nb, SCAN_BLOCK, 0, stream>>>(in, out, n, blockSums);
    scanCf_t<T><<<nb, SCAN_BLOCK, 0, stream>>>(out, n, blockSums, nb, totalOut);
}

extern "C" void kernel_launch(void* const* d_in, const int* in_sizes, int n_in,
                              void* d_out, int out_size, void* d_ws, size_t ws_size,
                              hipStream_t stream) {
    const float* pos = (const float*)d_in[0];
    const float* sdf = (const float*)d_in[1];
    const int* tet = (const int*)d_in[2];
    int V = in_sizes[1];
    int T = in_sizes[2] / 4;
    float* out = (float*)d_out;

    int NB = (V + BIN_VR - 1) / BIN_VR;
    int gB = (T + TETS_PER_BLOCK - 1) / TETS_PER_BLOCK;
    int nHist = NB * gB;

    char* p = (char*)d_ws;
    auto alloc = [&](size_t bytes) -> void* {
        void* r = (void*)p;
        p += (bytes + 255) & ~(size_t)255;
        return r;
    };
    u8*  ti8           = (u8*) alloc((size_t)T);
    u64* tetPack       = (u64*)alloc((size_t)T * 8);
    u64* tetScan       = (u64*)alloc((size_t)T * 8);
    u32* blockHist     = (u32*)alloc((size_t)nHist * 4);
    u32* blockHistScan = (u32*)alloc((size_t)nHist * 4);
    u32* binData       = (u32*)alloc((size_t)6 * T * 4);   // reused as idxmap
    u32* binProv       = (u32*)alloc((size_t)6 * T * 4);
    u32* bucketCnt     = (u32*)alloc((size_t)V * 4);
    u32* bucketStart   = (u32*)alloc((size_t)V * 4);
    u32* binTotals     = (u32*)alloc((size_t)BIN_VR * 4);
    u32* crossCnt      = (u32*)alloc((size_t)V * 4);
    u32* crossScan     = (u32*)alloc((size_t)V * 4);
    uint2* rec2        = (uint2*)alloc(((size_t)6 * T + 4 * (size_t)V) * 8);
    u32* bigList       = (u32*)alloc((size_t)V * 4);
    u64* blockSums64   = (u64*)alloc(2048 * 8);
    u32* blockSums32   = (u32*)alloc(2048 * 4);
    u64* meta64        = (u64*)alloc(8 * 8);
    u32* NePtr         = (u32*)(meta64 + 4);
    u32* NeInstPtr     = (u32*)(meta64 + 5);
    u32* bigCnt        = (u32*)(meta64 + 6);

    // u8 idxmap (6T bytes) aliases binData (24T bytes): binData's last
    // reader is k_binscatter2, idxmap's first writer is k_sortdedup
    // (strictly after).
    u8* idxmap = (u8*)binData;

    long long M = (2LL * T + 1) / 2;
    int Ngrid = (int)std::sqrt((double)M);
    while ((long long)Ngrid * Ngrid < M) ++Ngrid;
    if (Ngrid < 1) Ngrid = 1;
    long long uvFloats = 8LL * Ngrid * Ngrid;

    int gV4 = (V + 3) / 4;
    int gV8 = (V + 7) / 8;
    long long fw = (long long)Ngrid * Ngrid;          // >= T (M == T)
    if (fw < (long long)T) fw = T;
    int gFU = (int)((fw + 255) / 256);

    k_classify_hist<<<gB, 256, 0, stream>>>(tet, sdf, ti8, tetPack, blockHist,
                                            bigCnt, T, NB, gB);
    run_scan2<u64>(tetPack, tetScan, T, blockSums64, meta64, stream);
    run_scan2<u32>(blockHist, blockHistScan, nHist, blockSums32, NeInstPtr, stream);
    k_binfill<<<gB, 256, 0, stream>>>(tet, ti8, blockHistScan, binData, binProv,
                                      T, NB, gB);
    k_bincount2<<<NB, 256, 0, stream>>>(blockHistScan, NeInstPtr, binData,
                                        bucketCnt, bucketStart, binTotals,
                                        V, NB, gB);
    k_binscatter2<<<NB, 256, 0, stream>>>(blockHistScan, NeInstPtr, binData,
                                          binProv, binTotals, bucketStart,
                                          rec2, V, NB, gB);
    k_sortdedup<<<gV4, 256, 0, stream>>>(bucketCnt, bucketStart, rec2,
                                         idxmap, crossCnt, bigList, bigCnt, V);
    k_sortbig<<<1024, 256, 0, stream>>>(bigList, bigCnt, bucketCnt, bucketStart,
                                        rec2, idxmap, crossCnt);
    run_scan2<u32>(crossCnt, crossScan, V, blockSums32, NePtr, stream);
    k_verts<<<gV8, 256, 0, stream>>>(crossCnt, bucketStart, rec2, crossScan,
                                     pos, sdf, out, V);
    k_faces<<<gFU, 256, 0, stream>>>(tet, ti8, tetScan, idxmap, crossScan,
                                     meta64, NePtr, out, T, Ngrid, uvFloats);
}